// Round 8
// baseline (36.280 us; speedup 1.0000x reference)
//
#include <hip/hip_runtime.h>
#include <math.h>

#define NQ 12
#define NN 4096   // 2^12

typedef float f2 __attribute__((ext_vector_type(2)));  // (re, im)

__device__ __forceinline__ float2 cmulh(float2 a, float2 b) {
    return make_float2(a.x * b.x - a.y * b.y, a.x * b.y + a.y * b.x);
}

// Force a (uniform) value into an SGPR pair for the "s" asm operands.
__device__ __forceinline__ f2 uni(float2 a) {
    f2 r;
    r.x = __int_as_float(__builtin_amdgcn_readfirstlane(__float_as_int(a.x)));
    r.y = __int_as_float(__builtin_amdgcn_readfirstlane(__float_as_int(a.y)));
    return r;
}

// ---- packed complex arithmetic: 2 x v_pk_fma_f32 per complex MAC ----
// m = [mr, mi] (SGPR pair, uniform), b = [br, bi], acc = [ar, ai].
__device__ __forceinline__ void cmac_pk(f2& acc, f2 m, f2 b) {
    asm("v_pk_fma_f32 %0, %1, %2, %0 op_sel:[0,0,0] op_sel_hi:[0,1,1]\n\t"
        "v_pk_fma_f32 %0, %1, %2, %0 op_sel:[1,1,0] op_sel_hi:[1,0,1] neg_lo:[1,0,0]"
        : "+v"(acc) : "s"(m), "v"(b));
}
__device__ __forceinline__ void cmul_pk(f2& r, f2 m, f2 b) {
    asm("v_pk_mul_f32 %0, %1, %2 op_sel:[0,0] op_sel_hi:[0,1]\n\t"
        "v_pk_fma_f32 %0, %1, %2, %0 op_sel:[1,1,0] op_sel_hi:[1,0,1] neg_lo:[1,0,0]"
        : "=&v"(r) : "s"(m), "v"(b));
}

// Radix-2 butterfly on slot bit log2(D) over 8 slots.
template<int D>
__device__ __forceinline__ void stagepk8(f2 (&v)[8], f2 m00, f2 m01, f2 m10, f2 m11) {
    #pragma unroll
    for (int s = 0; s < 8; ++s) {
        if (s & D) continue;
        f2 va = v[s], vb = v[s | D];
        f2 r0, r1;
        cmul_pk(r0, m00, va); cmac_pk(r0, m01, vb);
        cmul_pk(r1, m10, va); cmac_pk(r1, m11, vb);
        v[s] = r0; v[s | D] = r1;
    }
}

// 512 threads/block, TWO batch rows per block (grid = B/2 = 1024, fully
// resident at 4 blocks/CU), 8 complex elements/thread. Single kernel: every
// thread redundantly computes the 12 uniform 2x2 matrices (fast trig) while
// the 8 global loads are in flight; readfirstlane pins them in SGPRs — the
// exact register shape R2-R6 validated (SGPR_Count 112), zero LDS traffic
// for matrices (R7's 1.57M bank-conflict regression removed).
// M_p = diag(e^{i phi},1) * u * diag(e^{i theta},1) * u * diag(e^{i a}, e^{i b}),
// u = (1/sqrt2)[[1,i],[i,1]], parameter index q = 11-p.
//
// Mappings (T = thread 9 bits, s = slot 3 bits):
//   A: i = T<<3 | s                         -> slot bits {0,1,2}
//   B: i = (T>>3)<<6 | s<<3 | (T&7)         -> slot bits {3,4,5}
//   C: i = (T>>6)<<9 | s<<6 | (T&63)        -> slot bits {6,7,8}
//   D: i = s<<9 | T                         -> slot bits {9,10,11}
// LDS layout: idx(i) = i + (i>>3) (stride-9/8 padding; 4608 f2 = 36 KB).
// A, B, C all keep i[11:9] == T[8:6] (the wave id) -> transposes A->B, B->C
// and the C-side write of C->D are wave-region-local (in-order DS pipe, no
// barrier). Only the D-read crosses waves -> barrier before it, and a second
// barrier after it (row 0 only) so row 1's A-writes can't race D-reads.
// Stores are non-temporal: output is never re-read; no-allocate keeps x
// L3-resident across graph replays.
__global__ __launch_bounds__(512, 8) void sq_layer(const float* __restrict__ x,
                                                   float* __restrict__ out,
                                                   const float* __restrict__ alphas,
                                                   const float* __restrict__ betas,
                                                   const float* __restrict__ thetas,
                                                   const float* __restrict__ phis) {
    __shared__ f2 lds[4608];  // 36 KB
    const int T = threadIdx.x;
    const size_t row0 = (size_t)blockIdx.x * 2;

    // ---- issue ALL global loads (both rows) first ----
    const float* px = x + row0 * (2 * NN) + (T << 3);
    float4 ra0 = *reinterpret_cast<const float4*>(px);
    float4 rb0 = *reinterpret_cast<const float4*>(px + 4);
    float4 ia0 = *reinterpret_cast<const float4*>(px + NN);
    float4 ib0 = *reinterpret_cast<const float4*>(px + NN + 4);
    float4 ra1 = *reinterpret_cast<const float4*>(px + 2 * NN);
    float4 rb1 = *reinterpret_cast<const float4*>(px + 2 * NN + 4);
    float4 ia1 = *reinterpret_cast<const float4*>(px + 3 * NN);
    float4 ib1 = *reinterpret_cast<const float4*>(px + 3 * NN + 4);

    // ---- uniform matrix computation (hides under the load burst) ----
    f2 Mat[48];
    #pragma unroll
    for (int p = 0; p < NQ; ++p) {
        int q = NQ - 1 - p;   // phase_shifts uses bit_{n-1-q}
        float av = alphas[q], bv = betas[q], tv = thetas[q], fv = phis[q];
        float sa = __sinf(av), ca = __cosf(av);
        float sb = __sinf(bv), cb = __cosf(bv);
        float st = __sinf(tv), ct = __cosf(tv);
        float sf = __sinf(fv), cf = __cosf(fv);
        float2 A  = make_float2(ca, sa);
        float2 Bb = make_float2(cb, sb);
        float2 F  = make_float2(cf, sf);
        float2 Tm  = make_float2(0.5f * (ct - 1.0f), 0.5f * st);  // (T-1)/2
        float2 Tp  = make_float2(0.5f * (ct + 1.0f), 0.5f * st);  // (T+1)/2
        float2 iTp = make_float2(-Tp.y, Tp.x);                    // i*(T+1)/2
        Mat[p * 4 + 0] = uni(cmulh(cmulh(F, Tm), A));
        Mat[p * 4 + 1] = uni(cmulh(cmulh(F, iTp), Bb));
        Mat[p * 4 + 2] = uni(cmulh(iTp, A));
        Mat[p * 4 + 3] = uni(cmulh(make_float2(-Tm.x, -Tm.y), Bb));
    }

    #pragma unroll
    for (int r = 0; r < 2; ++r) {
        f2 v[8];
        float4 ra = (r == 0) ? ra0 : ra1;
        float4 rb = (r == 0) ? rb0 : rb1;
        float4 ia = (r == 0) ? ia0 : ia1;
        float4 ib = (r == 0) ? ib0 : ib1;
        v[0] = f2{ra.x, ia.x}; v[1] = f2{ra.y, ia.y};
        v[2] = f2{ra.z, ia.z}; v[3] = f2{ra.w, ia.w};
        v[4] = f2{rb.x, ib.x}; v[5] = f2{rb.y, ib.y};
        v[6] = f2{rb.z, ib.z}; v[7] = f2{rb.w, ib.w};

        // ---- phase 1: bits 0,1,2 ----
        stagepk8<1>(v, Mat[0],  Mat[1],  Mat[2],  Mat[3]);
        stagepk8<2>(v, Mat[4],  Mat[5],  Mat[6],  Mat[7]);
        stagepk8<4>(v, Mat[8],  Mat[9],  Mat[10], Mat[11]);

        // ---- transpose A -> B (wave-region-local, no barrier) ----
        {
            f2* wp = lds + 9 * T;
            #pragma unroll
            for (int s = 0; s < 8; ++s) wp[s] = v[s];
        }
        {
            const f2* rp = lds + 72 * (T >> 3) + (T & 7);
            #pragma unroll
            for (int s = 0; s < 8; ++s) v[s] = rp[9 * s];
        }

        // ---- phase 2: bits 3,4,5 ----
        stagepk8<1>(v, Mat[12], Mat[13], Mat[14], Mat[15]);
        stagepk8<2>(v, Mat[16], Mat[17], Mat[18], Mat[19]);
        stagepk8<4>(v, Mat[20], Mat[21], Mat[22], Mat[23]);

        // ---- transpose B -> C (wave-region-local, no barrier) ----
        {
            f2* wp = lds + 72 * (T >> 3) + (T & 7);
            #pragma unroll
            for (int s = 0; s < 8; ++s) wp[9 * s] = v[s];
        }
        {
            const f2* rp = lds + 576 * (T >> 6) + (T & 63) + ((T & 63) >> 3);
            #pragma unroll
            for (int s = 0; s < 8; ++s) v[s] = rp[72 * s];
        }

        // ---- phase 3: bits 6,7,8 ----
        stagepk8<1>(v, Mat[24], Mat[25], Mat[26], Mat[27]);
        stagepk8<2>(v, Mat[28], Mat[29], Mat[30], Mat[31]);
        stagepk8<4>(v, Mat[32], Mat[33], Mat[34], Mat[35]);

        // ---- transpose C -> D: write C (own region), BARRIER, read D ----
        {
            f2* wp = lds + 576 * (T >> 6) + (T & 63) + ((T & 63) >> 3);
            #pragma unroll
            for (int s = 0; s < 8; ++s) wp[72 * s] = v[s];
        }
        __syncthreads();
        {
            const f2* rp = lds + T + (T >> 3);   // idx(s<<9 | T) = 576s + T + (T>>3)
            #pragma unroll
            for (int s = 0; s < 8; ++s) v[s] = rp[576 * s];
        }
        if (r == 0) __syncthreads();  // D-reads done before row 1's A-writes

        // ---- phase 4: bits 9,10,11 ----
        stagepk8<1>(v, Mat[36], Mat[37], Mat[38], Mat[39]);
        stagepk8<2>(v, Mat[40], Mat[41], Mat[42], Mat[43]);
        stagepk8<4>(v, Mat[44], Mat[45], Mat[46], Mat[47]);

        // ---- store (mapping D): i = s<<9 | T, wave-contiguous, non-temporal ----
        {
            float* po = out + (row0 + r) * (2 * NN);
            #pragma unroll
            for (int s = 0; s < 8; ++s) {
                int i = (s << 9) | T;
                __builtin_nontemporal_store(v[s].x, po + i);
                __builtin_nontemporal_store(v[s].y, po + NN + i);
            }
        }
    }
}

extern "C" void kernel_launch(void* const* d_in, const int* in_sizes, int n_in,
                              void* d_out, int out_size, void* d_ws, size_t ws_size,
                              hipStream_t stream) {
    const float* x      = (const float*)d_in[0];
    const float* alphas = (const float*)d_in[1];
    const float* betas  = (const float*)d_in[2];
    const float* thetas = (const float*)d_in[3];
    const float* phis   = (const float*)d_in[4];
    float* out = (float*)d_out;

    const int B = in_sizes[0] / (2 * NN);  // 2048

    hipLaunchKernelGGL(sq_layer, dim3(B / 2), dim3(512), 0, stream,
                       x, out, alphas, betas, thetas, phis);
}

// Round 9
// 32.643 us; speedup vs baseline: 1.1114x; 1.1114x over previous
//
#include <hip/hip_runtime.h>
#include <math.h>

#define NQ 12
#define NN 4096   // 2^12

typedef float f2 __attribute__((ext_vector_type(2)));  // (re, im) in a VGPR pair

__device__ __forceinline__ float2 cmulh(float2 a, float2 b) {
    return make_float2(a.x * b.x - a.y * b.y, a.x * b.y + a.y * b.x);
}

// ---- packed complex arithmetic: 2 x v_pk_fma_f32 per complex MAC ----
// m = [mr, mi] (SGPR pair, uniform, s_load-fed), b = [br, bi], acc = [ar, ai].
__device__ __forceinline__ void cmac_pk(f2& acc, f2 m, f2 b) {
    asm("v_pk_fma_f32 %0, %1, %2, %0 op_sel:[0,0,0] op_sel_hi:[0,1,1]\n\t"
        "v_pk_fma_f32 %0, %1, %2, %0 op_sel:[1,1,0] op_sel_hi:[1,0,1] neg_lo:[1,0,0]"
        : "+v"(acc) : "s"(m), "v"(b));
}
__device__ __forceinline__ void cmul_pk(f2& r, f2 m, f2 b) {
    asm("v_pk_mul_f32 %0, %1, %2 op_sel:[0,0] op_sel_hi:[0,1]\n\t"
        "v_pk_fma_f32 %0, %1, %2, %0 op_sel:[1,1,0] op_sel_hi:[1,0,1] neg_lo:[1,0,0]"
        : "=&v"(r) : "s"(m), "v"(b));
}

// Radix-2 butterfly on slot bit log2(D) over 8 slots.
template<int D>
__device__ __forceinline__ void stagepk8(f2 (&v)[8], f2 m00, f2 m01, f2 m10, f2 m11) {
    #pragma unroll
    for (int s = 0; s < 8; ++s) {
        if (s & D) continue;
        f2 va = v[s], vb = v[s | D];
        f2 r0, r1;
        cmul_pk(r0, m00, va); cmac_pk(r0, m01, vb);
        cmul_pk(r1, m10, va); cmac_pk(r1, m11, vb);
        v[s] = r0; v[s | D] = r1;
    }
}

// d_ws: Mg[p*4 + {m00,m01,m10,m11}] for bit position p = 0..11.
// M_p = diag(e^{i phi},1) * u * diag(e^{i theta},1) * u * diag(e^{i a}, e^{i b}),
// u = (1/sqrt2)[[1,i],[i,1]], parameter index q = 11-p.
// Fast trig: |err| ~1e-5, negligible vs the 0.11 absmax threshold.
__global__ void setup_mats(const float* __restrict__ alphas,
                           const float* __restrict__ betas,
                           const float* __restrict__ thetas,
                           const float* __restrict__ phis,
                           float2* __restrict__ Mg) {
    int t = threadIdx.x;
    if (t < NQ) {
        int p = t, q = NQ - 1 - p;
        float av = alphas[q], bv = betas[q], tv = thetas[q], fv = phis[q];
        float sa = __sinf(av), ca = __cosf(av);
        float sb = __sinf(bv), cb = __cosf(bv);
        float st = __sinf(tv), ct = __cosf(tv);
        float sf = __sinf(fv), cf = __cosf(fv);
        float2 A  = make_float2(ca, sa);
        float2 Bb = make_float2(cb, sb);
        float2 F  = make_float2(cf, sf);
        float2 Tm  = make_float2(0.5f * (ct - 1.0f), 0.5f * st);  // (T-1)/2
        float2 Tp  = make_float2(0.5f * (ct + 1.0f), 0.5f * st);  // (T+1)/2
        float2 iTp = make_float2(-Tp.y, Tp.x);                    // i*(T+1)/2
        Mg[p * 4 + 0] = cmulh(cmulh(F, Tm), A);
        Mg[p * 4 + 1] = cmulh(cmulh(F, iTp), Bb);
        Mg[p * 4 + 2] = cmulh(iTp, A);
        Mg[p * 4 + 3] = cmulh(make_float2(-Tm.x, -Tm.y), Bb);
    }
}

// 512 threads/block, TWO batch rows per block (grid = B/2 = 1024, fully
// resident at 4 blocks/CU = 32 waves/CU), 8 complex elements/thread.
// Mappings (T = thread 9 bits, s = slot 3 bits):
//   A: i = T<<3 | s                         -> slot bits {0,1,2}
//   B: i = (T>>3)<<6 | s<<3 | (T&7)         -> slot bits {3,4,5}
//   C: i = (T>>6)<<9 | s<<6 | (T&63)        -> slot bits {6,7,8}
//   D: i = s<<9 | T                         -> slot bits {9,10,11}
// LDS layout: idx(i) = i + (i>>3) (stride-9/8 padding; 4608 f2 = 36 KB).
// Every transpose pattern sits at the b64 4-access/bank floor (the ~1.57M
// SQ_LDS_BANK_CONFLICT seen in R7/R8 profiles is exactly 2 cyc x wave-b64-op
// count — inherent, not fixable). A, B, C all keep i[11:9] == T[8:6] (the
// wave id) -> transposes A->B, B->C and the C-side write of C->D are
// wave-region-local (in-order DS pipe, no barrier). Only the D-read crosses
// waves -> barrier before it, and a second barrier after it (row 0 only) so
// row 1's A-writes can't race other waves' D-reads. Both rows' global loads
// are issued at the very top so the full read burst is in flight during
// row-0 processing. Stores are non-temporal (output never re-read).
__global__ __launch_bounds__(512, 8) void sq_layer(const float* __restrict__ x,
                                                   const float2* __restrict__ Mgf,
                                                   float* __restrict__ out) {
    __shared__ f2 lds[4608];  // 36 KB
    const int T = threadIdx.x;
    const size_t row0 = (size_t)blockIdx.x * 2;
    const f2* Mg = (const f2*)Mgf;

    // ---- issue ALL global loads (both rows) first ----
    const float* px = x + row0 * (2 * NN) + (T << 3);
    float4 ra0 = *reinterpret_cast<const float4*>(px);
    float4 rb0 = *reinterpret_cast<const float4*>(px + 4);
    float4 ia0 = *reinterpret_cast<const float4*>(px + NN);
    float4 ib0 = *reinterpret_cast<const float4*>(px + NN + 4);
    float4 ra1 = *reinterpret_cast<const float4*>(px + 2 * NN);
    float4 rb1 = *reinterpret_cast<const float4*>(px + 2 * NN + 4);
    float4 ia1 = *reinterpret_cast<const float4*>(px + 3 * NN);
    float4 ib1 = *reinterpret_cast<const float4*>(px + 3 * NN + 4);

    #pragma unroll
    for (int r = 0; r < 2; ++r) {
        f2 v[8];
        float4 ra = (r == 0) ? ra0 : ra1;
        float4 rb = (r == 0) ? rb0 : rb1;
        float4 ia = (r == 0) ? ia0 : ia1;
        float4 ib = (r == 0) ? ib0 : ib1;
        v[0] = f2{ra.x, ia.x}; v[1] = f2{ra.y, ia.y};
        v[2] = f2{ra.z, ia.z}; v[3] = f2{ra.w, ia.w};
        v[4] = f2{rb.x, ib.x}; v[5] = f2{rb.y, ib.y};
        v[6] = f2{rb.z, ib.z}; v[7] = f2{rb.w, ib.w};

        // ---- phase 1: bits 0,1,2 ----
        stagepk8<1>(v, Mg[0],  Mg[1],  Mg[2],  Mg[3]);
        stagepk8<2>(v, Mg[4],  Mg[5],  Mg[6],  Mg[7]);
        stagepk8<4>(v, Mg[8],  Mg[9],  Mg[10], Mg[11]);

        // ---- transpose A -> B (wave-region-local, no barrier) ----
        {
            f2* wp = lds + 9 * T;
            #pragma unroll
            for (int s = 0; s < 8; ++s) wp[s] = v[s];
        }
        {
            const f2* rp = lds + 72 * (T >> 3) + (T & 7);
            #pragma unroll
            for (int s = 0; s < 8; ++s) v[s] = rp[9 * s];
        }

        // ---- phase 2: bits 3,4,5 ----
        stagepk8<1>(v, Mg[12], Mg[13], Mg[14], Mg[15]);
        stagepk8<2>(v, Mg[16], Mg[17], Mg[18], Mg[19]);
        stagepk8<4>(v, Mg[20], Mg[21], Mg[22], Mg[23]);

        // ---- transpose B -> C (wave-region-local, no barrier) ----
        {
            f2* wp = lds + 72 * (T >> 3) + (T & 7);
            #pragma unroll
            for (int s = 0; s < 8; ++s) wp[9 * s] = v[s];
        }
        {
            const f2* rp = lds + 576 * (T >> 6) + (T & 63) + ((T & 63) >> 3);
            #pragma unroll
            for (int s = 0; s < 8; ++s) v[s] = rp[72 * s];
        }

        // ---- phase 3: bits 6,7,8 ----
        stagepk8<1>(v, Mg[24], Mg[25], Mg[26], Mg[27]);
        stagepk8<2>(v, Mg[28], Mg[29], Mg[30], Mg[31]);
        stagepk8<4>(v, Mg[32], Mg[33], Mg[34], Mg[35]);

        // ---- transpose C -> D: write C (own region), BARRIER, read D ----
        {
            f2* wp = lds + 576 * (T >> 6) + (T & 63) + ((T & 63) >> 3);
            #pragma unroll
            for (int s = 0; s < 8; ++s) wp[72 * s] = v[s];
        }
        __syncthreads();
        {
            const f2* rp = lds + T + (T >> 3);   // idx(s<<9 | T) = 576s + T + (T>>3)
            #pragma unroll
            for (int s = 0; s < 8; ++s) v[s] = rp[576 * s];
        }
        if (r == 0) __syncthreads();  // D-reads done before row 1's A-writes

        // ---- phase 4: bits 9,10,11 ----
        stagepk8<1>(v, Mg[36], Mg[37], Mg[38], Mg[39]);
        stagepk8<2>(v, Mg[40], Mg[41], Mg[42], Mg[43]);
        stagepk8<4>(v, Mg[44], Mg[45], Mg[46], Mg[47]);

        // ---- store (mapping D): i = s<<9 | T, wave-contiguous, non-temporal ----
        {
            float* po = out + (row0 + r) * (2 * NN);
            #pragma unroll
            for (int s = 0; s < 8; ++s) {
                int i = (s << 9) | T;
                __builtin_nontemporal_store(v[s].x, po + i);
                __builtin_nontemporal_store(v[s].y, po + NN + i);
            }
        }
    }
}

extern "C" void kernel_launch(void* const* d_in, const int* in_sizes, int n_in,
                              void* d_out, int out_size, void* d_ws, size_t ws_size,
                              hipStream_t stream) {
    const float* x      = (const float*)d_in[0];
    const float* alphas = (const float*)d_in[1];
    const float* betas  = (const float*)d_in[2];
    const float* thetas = (const float*)d_in[3];
    const float* phis   = (const float*)d_in[4];
    float* out = (float*)d_out;
    float2* Mg = (float2*)d_ws;   // 48 float2 = 384 B

    const int B = in_sizes[0] / (2 * NN);  // 2048

    hipLaunchKernelGGL(setup_mats, dim3(1), dim3(64), 0, stream,
                       alphas, betas, thetas, phis, Mg);
    hipLaunchKernelGGL(sq_layer, dim3(B / 2), dim3(512), 0, stream,
                       x, (const float2*)Mg, out);
}

// Round 10
// 32.215 us; speedup vs baseline: 1.1262x; 1.0133x over previous
//
#include <hip/hip_runtime.h>
#include <math.h>

#define NQ 12
#define NN 4096   // 2^12

typedef float f2 __attribute__((ext_vector_type(2)));  // (re, im) in a VGPR pair
typedef float f4 __attribute__((ext_vector_type(4)));

__device__ __forceinline__ float2 cmulh(float2 a, float2 b) {
    return make_float2(a.x * b.x - a.y * b.y, a.x * b.y + a.y * b.x);
}

// Unsinkable 16B global load: volatile asm pins the result registers live
// from issue to consumption (the compiler sank plain C++ prefetch loads —
// VGPR_Count=32 in R7/R8 profiles proves it).
__device__ __forceinline__ f4 gload4(const float* p) {
    f4 d;
    asm volatile("global_load_dwordx4 %0, %1, off" : "=v"(d) : "v"(p));
    return d;
}

// ---- packed complex arithmetic: 2 x v_pk_fma_f32 per complex MAC ----
// m = [mr, mi] (SGPR pair, uniform, s_load-fed), b = [br, bi], acc = [ar, ai].
__device__ __forceinline__ void cmac_pk(f2& acc, f2 m, f2 b) {
    asm("v_pk_fma_f32 %0, %1, %2, %0 op_sel:[0,0,0] op_sel_hi:[0,1,1]\n\t"
        "v_pk_fma_f32 %0, %1, %2, %0 op_sel:[1,1,0] op_sel_hi:[1,0,1] neg_lo:[1,0,0]"
        : "+v"(acc) : "s"(m), "v"(b));
}
__device__ __forceinline__ void cmul_pk(f2& r, f2 m, f2 b) {
    asm("v_pk_mul_f32 %0, %1, %2 op_sel:[0,0] op_sel_hi:[0,1]\n\t"
        "v_pk_fma_f32 %0, %1, %2, %0 op_sel:[1,1,0] op_sel_hi:[1,0,1] neg_lo:[1,0,0]"
        : "=&v"(r) : "s"(m), "v"(b));
}

// Radix-2 butterfly on slot bit log2(D) over 8 slots.
template<int D>
__device__ __forceinline__ void stagepk8(f2 (&v)[8], f2 m00, f2 m01, f2 m10, f2 m11) {
    #pragma unroll
    for (int s = 0; s < 8; ++s) {
        if (s & D) continue;
        f2 va = v[s], vb = v[s | D];
        f2 r0, r1;
        cmul_pk(r0, m00, va); cmac_pk(r0, m01, vb);
        cmul_pk(r1, m10, va); cmac_pk(r1, m11, vb);
        v[s] = r0; v[s | D] = r1;
    }
}

// d_ws: Mg[p*4 + {m00,m01,m10,m11}] for bit position p = 0..11.
// M_p = diag(e^{i phi},1) * u * diag(e^{i theta},1) * u * diag(e^{i a}, e^{i b}),
// u = (1/sqrt2)[[1,i],[i,1]], parameter index q = 11-p.
__global__ void setup_mats(const float* __restrict__ alphas,
                           const float* __restrict__ betas,
                           const float* __restrict__ thetas,
                           const float* __restrict__ phis,
                           float2* __restrict__ Mg) {
    int t = threadIdx.x;
    if (t < NQ) {
        int p = t, q = NQ - 1 - p;
        float av = alphas[q], bv = betas[q], tv = thetas[q], fv = phis[q];
        float sa = __sinf(av), ca = __cosf(av);
        float sb = __sinf(bv), cb = __cosf(bv);
        float st = __sinf(tv), ct = __cosf(tv);
        float sf = __sinf(fv), cf = __cosf(fv);
        float2 A  = make_float2(ca, sa);
        float2 Bb = make_float2(cb, sb);
        float2 F  = make_float2(cf, sf);
        float2 Tm  = make_float2(0.5f * (ct - 1.0f), 0.5f * st);  // (T-1)/2
        float2 Tp  = make_float2(0.5f * (ct + 1.0f), 0.5f * st);  // (T+1)/2
        float2 iTp = make_float2(-Tp.y, Tp.x);                    // i*(T+1)/2
        Mg[p * 4 + 0] = cmulh(cmulh(F, Tm), A);
        Mg[p * 4 + 1] = cmulh(cmulh(F, iTp), Bb);
        Mg[p * 4 + 2] = cmulh(iTp, A);
        Mg[p * 4 + 3] = cmulh(make_float2(-Tm.x, -Tm.y), Bb);
    }
}

// 512 threads/block, TWO batch rows per block (grid = B/2 = 1024), 8 complex
// elements/thread. Row-1 loads are issued via unsinkable asm at the top and
// drained by a manual vmcnt(0)+sched_barrier after row-0 phase 4 (by which
// point they are long complete) — true prefetch, unlike the compiler-sunk
// C++ loads of R5-R9.
// Mappings (T = thread 9 bits, s = slot 3 bits):
//   A: i = T<<3 | s                         -> slot bits {0,1,2}
//   B: i = (T>>3)<<6 | s<<3 | (T&7)         -> slot bits {3,4,5}
//   C: i = (T>>6)<<9 | s<<6 | (T&63)        -> slot bits {6,7,8}
//   D: i = s<<9 | T                         -> slot bits {9,10,11}
// LDS layout: idx(i) = i + (i>>3) (stride-9/8 padding; 4608 f2 = 36 KB).
// Transposes A->B, B->C and the C-write of C->D are wave-region-local
// (i[11:9]==T[8:6]; in-order DS pipe, no barrier). Only the D-read crosses
// waves -> barrier before it + one after (row 0 only). ~1.57M
// SQ_LDS_BANK_CONFLICT is the inherent b64 4-access/bank floor, not fixable.
// Stores non-temporal (output never re-read).
__global__ __launch_bounds__(512, 8) void sq_layer(const float* __restrict__ x,
                                                   const float2* __restrict__ Mgf,
                                                   float* __restrict__ out) {
    __shared__ f2 lds[4608];  // 36 KB
    const int T = threadIdx.x;
    const size_t row0 = (size_t)blockIdx.x * 2;
    const f2* Mg = (const f2*)Mgf;

    const float* px = x + row0 * (2 * NN) + (T << 3);
    // row-0 loads (compiler-managed; consumed immediately below)
    float4 ra0 = *reinterpret_cast<const float4*>(px);
    float4 rb0 = *reinterpret_cast<const float4*>(px + 4);
    float4 ia0 = *reinterpret_cast<const float4*>(px + NN);
    float4 ib0 = *reinterpret_cast<const float4*>(px + NN + 4);
    // row-1 loads: pinned in flight across all of row-0's compute
    f4 ra1 = gload4(px + 2 * NN);
    f4 rb1 = gload4(px + 2 * NN + 4);
    f4 ia1 = gload4(px + 3 * NN);
    f4 ib1 = gload4(px + 3 * NN + 4);

    #pragma unroll
    for (int r = 0; r < 2; ++r) {
        f2 v[8];
        if (r == 0) {
            v[0] = f2{ra0.x, ia0.x}; v[1] = f2{ra0.y, ia0.y};
            v[2] = f2{ra0.z, ia0.z}; v[3] = f2{ra0.w, ia0.w};
            v[4] = f2{rb0.x, ib0.x}; v[5] = f2{rb0.y, ib0.y};
            v[6] = f2{rb0.z, ib0.z}; v[7] = f2{rb0.w, ib0.w};
        } else {
            v[0] = f2{ra1.x, ia1.x}; v[1] = f2{ra1.y, ia1.y};
            v[2] = f2{ra1.z, ia1.z}; v[3] = f2{ra1.w, ia1.w};
            v[4] = f2{rb1.x, ib1.x}; v[5] = f2{rb1.y, ib1.y};
            v[6] = f2{rb1.z, ib1.z}; v[7] = f2{rb1.w, ib1.w};
        }

        // ---- phase 1: bits 0,1,2 ----
        stagepk8<1>(v, Mg[0],  Mg[1],  Mg[2],  Mg[3]);
        stagepk8<2>(v, Mg[4],  Mg[5],  Mg[6],  Mg[7]);
        stagepk8<4>(v, Mg[8],  Mg[9],  Mg[10], Mg[11]);

        // ---- transpose A -> B (wave-region-local, no barrier) ----
        {
            f2* wp = lds + 9 * T;
            #pragma unroll
            for (int s = 0; s < 8; ++s) wp[s] = v[s];
        }
        {
            const f2* rp = lds + 72 * (T >> 3) + (T & 7);
            #pragma unroll
            for (int s = 0; s < 8; ++s) v[s] = rp[9 * s];
        }

        // ---- phase 2: bits 3,4,5 ----
        stagepk8<1>(v, Mg[12], Mg[13], Mg[14], Mg[15]);
        stagepk8<2>(v, Mg[16], Mg[17], Mg[18], Mg[19]);
        stagepk8<4>(v, Mg[20], Mg[21], Mg[22], Mg[23]);

        // ---- transpose B -> C (wave-region-local, no barrier) ----
        {
            f2* wp = lds + 72 * (T >> 3) + (T & 7);
            #pragma unroll
            for (int s = 0; s < 8; ++s) wp[9 * s] = v[s];
        }
        {
            const f2* rp = lds + 576 * (T >> 6) + (T & 63) + ((T & 63) >> 3);
            #pragma unroll
            for (int s = 0; s < 8; ++s) v[s] = rp[72 * s];
        }

        // ---- phase 3: bits 6,7,8 ----
        stagepk8<1>(v, Mg[24], Mg[25], Mg[26], Mg[27]);
        stagepk8<2>(v, Mg[28], Mg[29], Mg[30], Mg[31]);
        stagepk8<4>(v, Mg[32], Mg[33], Mg[34], Mg[35]);

        // ---- transpose C -> D: write C (own region), BARRIER, read D ----
        {
            f2* wp = lds + 576 * (T >> 6) + (T & 63) + ((T & 63) >> 3);
            #pragma unroll
            for (int s = 0; s < 8; ++s) wp[72 * s] = v[s];
        }
        __syncthreads();
        {
            const f2* rp = lds + T + (T >> 3);   // idx(s<<9 | T) = 576s + T + (T>>3)
            #pragma unroll
            for (int s = 0; s < 8; ++s) v[s] = rp[576 * s];
        }
        if (r == 0) __syncthreads();  // D-reads done before row 1's A-writes

        // ---- phase 4: bits 9,10,11 ----
        stagepk8<1>(v, Mg[36], Mg[37], Mg[38], Mg[39]);
        stagepk8<2>(v, Mg[40], Mg[41], Mg[42], Mg[43]);
        stagepk8<4>(v, Mg[44], Mg[45], Mg[46], Mg[47]);

        if (r == 0) {
            // Drain the row-1 asm loads (issued ~3 us ago — wait is free) and
            // fence scheduling: register uses of asm outputs may otherwise be
            // hoisted above the waitcnt (rule #18).
            asm volatile("s_waitcnt vmcnt(0)" ::: "memory");
            __builtin_amdgcn_sched_barrier(0);
        }

        // ---- store (mapping D): i = s<<9 | T, wave-contiguous, non-temporal ----
        {
            float* po = out + (row0 + r) * (2 * NN);
            #pragma unroll
            for (int s = 0; s < 8; ++s) {
                int i = (s << 9) | T;
                __builtin_nontemporal_store(v[s].x, po + i);
                __builtin_nontemporal_store(v[s].y, po + NN + i);
            }
        }
    }
}

extern "C" void kernel_launch(void* const* d_in, const int* in_sizes, int n_in,
                              void* d_out, int out_size, void* d_ws, size_t ws_size,
                              hipStream_t stream) {
    const float* x      = (const float*)d_in[0];
    const float* alphas = (const float*)d_in[1];
    const float* betas  = (const float*)d_in[2];
    const float* thetas = (const float*)d_in[3];
    const float* phis   = (const float*)d_in[4];
    float* out = (float*)d_out;
    float2* Mg = (float2*)d_ws;   // 48 float2 = 384 B

    const int B = in_sizes[0] / (2 * NN);  // 2048

    hipLaunchKernelGGL(setup_mats, dim3(1), dim3(64), 0, stream,
                       alphas, betas, thetas, phis, Mg);
    hipLaunchKernelGGL(sq_layer, dim3(B / 2), dim3(512), 0, stream,
                       x, (const float2*)Mg, out);
}

// Round 11
// 29.810 us; speedup vs baseline: 1.2171x; 1.0807x over previous
//
#include <hip/hip_runtime.h>
#include <math.h>

#define NQ 12
#define NN 4096   // 2^12

typedef float f2 __attribute__((ext_vector_type(2)));  // (re, im)

__device__ __forceinline__ float2 cmulh(float2 a, float2 b) {
    return make_float2(a.x * b.x - a.y * b.y, a.x * b.y + a.y * b.x);
}

// Broadcast LDS value -> SGPR pair (uniform across the wave by construction).
__device__ __forceinline__ f2 rfl2(f2 a) {
    f2 r;
    r.x = __int_as_float(__builtin_amdgcn_readfirstlane(__float_as_int(a.x)));
    r.y = __int_as_float(__builtin_amdgcn_readfirstlane(__float_as_int(a.y)));
    return r;
}

// ---- packed complex arithmetic: 2 x v_pk_fma_f32 per complex MAC ----
// m = [mr, mi] (SGPR pair, uniform), b = [br, bi], acc = [ar, ai].
__device__ __forceinline__ void cmac_pk(f2& acc, f2 m, f2 b) {
    asm("v_pk_fma_f32 %0, %1, %2, %0 op_sel:[0,0,0] op_sel_hi:[0,1,1]\n\t"
        "v_pk_fma_f32 %0, %1, %2, %0 op_sel:[1,1,0] op_sel_hi:[1,0,1] neg_lo:[1,0,0]"
        : "+v"(acc) : "s"(m), "v"(b));
}
__device__ __forceinline__ void cmul_pk(f2& r, f2 m, f2 b) {
    asm("v_pk_mul_f32 %0, %1, %2 op_sel:[0,0] op_sel_hi:[0,1]\n\t"
        "v_pk_fma_f32 %0, %1, %2, %0 op_sel:[1,1,0] op_sel_hi:[1,0,1] neg_lo:[1,0,0]"
        : "=&v"(r) : "s"(m), "v"(b));
}

// Radix-2 butterfly on slot bit log2(D) over 8 slots.
template<int D>
__device__ __forceinline__ void stagepk8(f2 (&v)[8], f2 m00, f2 m01, f2 m10, f2 m11) {
    #pragma unroll
    for (int s = 0; s < 8; ++s) {
        if (s & D) continue;
        f2 va = v[s], vb = v[s | D];
        f2 r0, r1;
        cmul_pk(r0, m00, va); cmac_pk(r0, m01, vb);
        cmul_pk(r1, m10, va); cmac_pk(r1, m11, vb);
        v[s] = r0; v[s | D] = r1;
    }
}

// Stage with its 2x2 matrix pulled from LDS at the call site: 4 broadcast
// ds_read_b64 (same-address -> conflict-free) + 8 readfirstlane -> only 16
// SGPRs live per stage (R8's failure was pinning 96 at once; R7's was "v"
// operands re-read with lgkm stalls inside the stage chain).
template<int D>
__device__ __forceinline__ void stage_m(f2 (&v)[8], const f2* m) {
    f2 m00 = rfl2(m[0]), m01 = rfl2(m[1]), m10 = rfl2(m[2]), m11 = rfl2(m[3]);
    stagepk8<D>(v, m00, m01, m10, m11);
}

// Single kernel. 512 threads/block, TWO batch rows per block (grid = B/2 =
// 1024, fully resident at 4 blocks/CU), 8 complex elements/thread.
// Threads 0..11 compute the 12 per-bit matrices into Msh (fast trig, hidden
// under the global-load burst), one barrier, then per-stage broadcast reads.
// M_p = diag(e^{i phi},1) * u * diag(e^{i theta},1) * u * diag(e^{i a}, e^{i b}),
// u = (1/sqrt2)[[1,i],[i,1]], parameter index q = 11-p.
//
// Mappings (T = thread 9 bits, s = slot 3 bits):
//   A: i = T<<3 | s                         -> slot bits {0,1,2}
//   B: i = (T>>3)<<6 | s<<3 | (T&7)         -> slot bits {3,4,5}
//   C: i = (T>>6)<<9 | s<<6 | (T&63)        -> slot bits {6,7,8}
//   D: i = s<<9 | T                         -> slot bits {9,10,11}
// LDS layout: idx(i) = i + (i>>3) (stride-9/8 padding; 4608 f2 = 36 KB).
// Transposes A->B, B->C and the C-write of C->D are wave-region-local
// (i[11:9]==T[8:6]; in-order DS pipe, no barrier). Only the D-read crosses
// waves -> barrier before it + one after (row 0 only). ~1.57M
// SQ_LDS_BANK_CONFLICT is the inherent b64 4-access/bank floor (2 cyc x
// wave-b64-op count), not fixable. Stores non-temporal (output never
// re-read; keeps x L3-resident across replays).
__global__ __launch_bounds__(512, 8) void sq_layer(const float* __restrict__ x,
                                                   float* __restrict__ out,
                                                   const float* __restrict__ alphas,
                                                   const float* __restrict__ betas,
                                                   const float* __restrict__ thetas,
                                                   const float* __restrict__ phis) {
    __shared__ f2 lds[4608];  // 36 KB
    __shared__ f2 Msh[48];    // +384 B
    const int T = threadIdx.x;
    const size_t row0 = (size_t)blockIdx.x * 2;

    // ---- issue ALL global loads (both rows) first ----
    const float* px = x + row0 * (2 * NN) + (T << 3);
    float4 ra0 = *reinterpret_cast<const float4*>(px);
    float4 rb0 = *reinterpret_cast<const float4*>(px + 4);
    float4 ia0 = *reinterpret_cast<const float4*>(px + NN);
    float4 ib0 = *reinterpret_cast<const float4*>(px + NN + 4);
    float4 ra1 = *reinterpret_cast<const float4*>(px + 2 * NN);
    float4 rb1 = *reinterpret_cast<const float4*>(px + 2 * NN + 4);
    float4 ia1 = *reinterpret_cast<const float4*>(px + 3 * NN);
    float4 ib1 = *reinterpret_cast<const float4*>(px + 3 * NN + 4);

    // ---- per-block matrix setup (hides under the load burst) ----
    if (T < NQ) {
        int p = T, q = NQ - 1 - p;
        float av = alphas[q], bv = betas[q], tv = thetas[q], fv = phis[q];
        float sa = __sinf(av), ca = __cosf(av);
        float sb = __sinf(bv), cb = __cosf(bv);
        float st = __sinf(tv), ct = __cosf(tv);
        float sf = __sinf(fv), cf = __cosf(fv);
        float2 A  = make_float2(ca, sa);
        float2 Bb = make_float2(cb, sb);
        float2 F  = make_float2(cf, sf);
        float2 Tm  = make_float2(0.5f * (ct - 1.0f), 0.5f * st);  // (T-1)/2
        float2 Tp  = make_float2(0.5f * (ct + 1.0f), 0.5f * st);  // (T+1)/2
        float2 iTp = make_float2(-Tp.y, Tp.x);                    // i*(T+1)/2
        float2 m00 = cmulh(cmulh(F, Tm), A);
        float2 m01 = cmulh(cmulh(F, iTp), Bb);
        float2 m10 = cmulh(iTp, A);
        float2 m11 = cmulh(make_float2(-Tm.x, -Tm.y), Bb);
        Msh[p * 4 + 0] = f2{m00.x, m00.y};
        Msh[p * 4 + 1] = f2{m01.x, m01.y};
        Msh[p * 4 + 2] = f2{m10.x, m10.y};
        Msh[p * 4 + 3] = f2{m11.x, m11.y};
    }
    __syncthreads();  // Msh visible to all waves

    #pragma unroll
    for (int r = 0; r < 2; ++r) {
        f2 v[8];
        if (r == 0) {
            v[0] = f2{ra0.x, ia0.x}; v[1] = f2{ra0.y, ia0.y};
            v[2] = f2{ra0.z, ia0.z}; v[3] = f2{ra0.w, ia0.w};
            v[4] = f2{rb0.x, ib0.x}; v[5] = f2{rb0.y, ib0.y};
            v[6] = f2{rb0.z, ib0.z}; v[7] = f2{rb0.w, ib0.w};
        } else {
            v[0] = f2{ra1.x, ia1.x}; v[1] = f2{ra1.y, ia1.y};
            v[2] = f2{ra1.z, ia1.z}; v[3] = f2{ra1.w, ia1.w};
            v[4] = f2{rb1.x, ib1.x}; v[5] = f2{rb1.y, ib1.y};
            v[6] = f2{rb1.z, ib1.z}; v[7] = f2{rb1.w, ib1.w};
        }

        // ---- phase 1: bits 0,1,2 ----
        stage_m<1>(v, Msh + 0);
        stage_m<2>(v, Msh + 4);
        stage_m<4>(v, Msh + 8);

        // ---- transpose A -> B (wave-region-local, no barrier) ----
        {
            f2* wp = lds + 9 * T;
            #pragma unroll
            for (int s = 0; s < 8; ++s) wp[s] = v[s];
        }
        {
            const f2* rp = lds + 72 * (T >> 3) + (T & 7);
            #pragma unroll
            for (int s = 0; s < 8; ++s) v[s] = rp[9 * s];
        }

        // ---- phase 2: bits 3,4,5 ----
        stage_m<1>(v, Msh + 12);
        stage_m<2>(v, Msh + 16);
        stage_m<4>(v, Msh + 20);

        // ---- transpose B -> C (wave-region-local, no barrier) ----
        {
            f2* wp = lds + 72 * (T >> 3) + (T & 7);
            #pragma unroll
            for (int s = 0; s < 8; ++s) wp[9 * s] = v[s];
        }
        {
            const f2* rp = lds + 576 * (T >> 6) + (T & 63) + ((T & 63) >> 3);
            #pragma unroll
            for (int s = 0; s < 8; ++s) v[s] = rp[72 * s];
        }

        // ---- phase 3: bits 6,7,8 ----
        stage_m<1>(v, Msh + 24);
        stage_m<2>(v, Msh + 28);
        stage_m<4>(v, Msh + 32);

        // ---- transpose C -> D: write C (own region), BARRIER, read D ----
        {
            f2* wp = lds + 576 * (T >> 6) + (T & 63) + ((T & 63) >> 3);
            #pragma unroll
            for (int s = 0; s < 8; ++s) wp[72 * s] = v[s];
        }
        __syncthreads();
        {
            const f2* rp = lds + T + (T >> 3);   // idx(s<<9 | T) = 576s + T + (T>>3)
            #pragma unroll
            for (int s = 0; s < 8; ++s) v[s] = rp[576 * s];
        }
        if (r == 0) __syncthreads();  // D-reads done before row 1's A-writes

        // ---- phase 4: bits 9,10,11 ----
        stage_m<1>(v, Msh + 36);
        stage_m<2>(v, Msh + 40);
        stage_m<4>(v, Msh + 44);

        // ---- store (mapping D): i = s<<9 | T, wave-contiguous, non-temporal ----
        {
            float* po = out + (row0 + r) * (2 * NN);
            #pragma unroll
            for (int s = 0; s < 8; ++s) {
                int i = (s << 9) | T;
                __builtin_nontemporal_store(v[s].x, po + i);
                __builtin_nontemporal_store(v[s].y, po + NN + i);
            }
        }
    }
}

extern "C" void kernel_launch(void* const* d_in, const int* in_sizes, int n_in,
                              void* d_out, int out_size, void* d_ws, size_t ws_size,
                              hipStream_t stream) {
    const float* x      = (const float*)d_in[0];
    const float* alphas = (const float*)d_in[1];
    const float* betas  = (const float*)d_in[2];
    const float* thetas = (const float*)d_in[3];
    const float* phis   = (const float*)d_in[4];
    float* out = (float*)d_out;

    const int B = in_sizes[0] / (2 * NN);  // 2048

    hipLaunchKernelGGL(sq_layer, dim3(B / 2), dim3(512), 0, stream,
                       x, out, alphas, betas, thetas, phis);
}

// Round 12
// 29.231 us; speedup vs baseline: 1.2412x; 1.0198x over previous
//
#include <hip/hip_runtime.h>
#include <math.h>

#define NQ 12
#define NN 4096   // 2^12

typedef float f2 __attribute__((ext_vector_type(2)));  // (re, im)
typedef float f4 __attribute__((ext_vector_type(4)));

__device__ __forceinline__ float2 cmulh(float2 a, float2 b) {
    return make_float2(a.x * b.x - a.y * b.y, a.x * b.y + a.y * b.x);
}

// Broadcast (wave-uniform) value -> SGPR pair. Used ONCE per kernel on LDS
// reads — cheap producers, unlike R8's trig chains that strangled the
// allocator. R2/R3/R6 prove SGPR_Count=112 (96 matrix SGPRs) allocates fine.
__device__ __forceinline__ f2 rfl2(f2 a) {
    f2 r;
    r.x = __int_as_float(__builtin_amdgcn_readfirstlane(__float_as_int(a.x)));
    r.y = __int_as_float(__builtin_amdgcn_readfirstlane(__float_as_int(a.y)));
    return r;
}

// ---- packed complex arithmetic: 2 x v_pk_fma_f32 per complex MAC ----
// m = [mr, mi] (SGPR pair, uniform), b = [br, bi], acc = [ar, ai].
__device__ __forceinline__ void cmac_pk(f2& acc, f2 m, f2 b) {
    asm("v_pk_fma_f32 %0, %1, %2, %0 op_sel:[0,0,0] op_sel_hi:[0,1,1]\n\t"
        "v_pk_fma_f32 %0, %1, %2, %0 op_sel:[1,1,0] op_sel_hi:[1,0,1] neg_lo:[1,0,0]"
        : "+v"(acc) : "s"(m), "v"(b));
}
__device__ __forceinline__ void cmul_pk(f2& r, f2 m, f2 b) {
    asm("v_pk_mul_f32 %0, %1, %2 op_sel:[0,0] op_sel_hi:[0,1]\n\t"
        "v_pk_fma_f32 %0, %1, %2, %0 op_sel:[1,1,0] op_sel_hi:[1,0,1] neg_lo:[1,0,0]"
        : "=&v"(r) : "s"(m), "v"(b));
}

// Radix-2 butterfly on slot bit log2(D) over 8 slots.
template<int D>
__device__ __forceinline__ void stagepk8(f2 (&v)[8], f2 m00, f2 m01, f2 m10, f2 m11) {
    #pragma unroll
    for (int s = 0; s < 8; ++s) {
        if (s & D) continue;
        f2 va = v[s], vb = v[s | D];
        f2 r0, r1;
        cmul_pk(r0, m00, va); cmac_pk(r0, m01, vb);
        cmul_pk(r1, m10, va); cmac_pk(r1, m11, vb);
        v[s] = r0; v[s | D] = r1;
    }
}

// Single kernel. 512 threads/block, TWO batch rows per block (grid = B/2 =
// 1024, fully resident at 4 blocks/CU = the 32-wave/CU HW cap), 8 complex
// elements/thread. Threads 0..11 compute the 12 per-bit matrices into Msh
// (fast trig, hidden under the global-load burst); after one barrier, ALL 48
// complex values are pinned to SGPRs via 24 ds_read_b128 + 96 readfirstlane
// — per-stage broadcast DS reads (96 b64/thread in R11, ~6 us of per-CU DS
// pipe) are eliminated.
// M_p = diag(e^{i phi},1) * u * diag(e^{i theta},1) * u * diag(e^{i a}, e^{i b}),
// u = (1/sqrt2)[[1,i],[i,1]], parameter index q = 11-p.
//
// Mappings (T = thread 9 bits, s = slot 3 bits):
//   A: i = T<<3 | s                         -> slot bits {0,1,2}
//   B: i = (T>>3)<<6 | s<<3 | (T&7)         -> slot bits {3,4,5}
//   C: i = (T>>6)<<9 | s<<6 | (T&63)        -> slot bits {6,7,8}
//   D: i = s<<9 | T                         -> slot bits {9,10,11}
// LDS layout: idx(i) = i + (i>>3) (stride-9/8 padding; 4608 f2 = 36 KB).
// Transposes A->B, B->C and the C-write of C->D are wave-region-local
// (i[11:9]==T[8:6]; in-order DS pipe, no barrier). Only the D-read crosses
// waves -> barrier before it + one after (row 0 only). Residual
// SQ_LDS_BANK_CONFLICT = 1 cyc per wave-b64 op (verified exact in R10) is
// the b64 floor. Stores non-temporal (output never re-read).
__global__ __launch_bounds__(512, 8) void sq_layer(const float* __restrict__ x,
                                                   float* __restrict__ out,
                                                   const float* __restrict__ alphas,
                                                   const float* __restrict__ betas,
                                                   const float* __restrict__ thetas,
                                                   const float* __restrict__ phis) {
    __shared__ f2 lds[4608];              // 36 KB
    __shared__ __align__(16) f2 Msh[48];  // +384 B
    const int T = threadIdx.x;
    const size_t row0 = (size_t)blockIdx.x * 2;

    // ---- issue ALL global loads (both rows) first ----
    const float* px = x + row0 * (2 * NN) + (T << 3);
    float4 ra0 = *reinterpret_cast<const float4*>(px);
    float4 rb0 = *reinterpret_cast<const float4*>(px + 4);
    float4 ia0 = *reinterpret_cast<const float4*>(px + NN);
    float4 ib0 = *reinterpret_cast<const float4*>(px + NN + 4);
    float4 ra1 = *reinterpret_cast<const float4*>(px + 2 * NN);
    float4 rb1 = *reinterpret_cast<const float4*>(px + 2 * NN + 4);
    float4 ia1 = *reinterpret_cast<const float4*>(px + 3 * NN);
    float4 ib1 = *reinterpret_cast<const float4*>(px + 3 * NN + 4);

    // ---- per-block matrix setup (hides under the load burst) ----
    if (T < NQ) {
        int p = T, q = NQ - 1 - p;
        float av = alphas[q], bv = betas[q], tv = thetas[q], fv = phis[q];
        float sa = __sinf(av), ca = __cosf(av);
        float sb = __sinf(bv), cb = __cosf(bv);
        float st = __sinf(tv), ct = __cosf(tv);
        float sf = __sinf(fv), cf = __cosf(fv);
        float2 A  = make_float2(ca, sa);
        float2 Bb = make_float2(cb, sb);
        float2 F  = make_float2(cf, sf);
        float2 Tm  = make_float2(0.5f * (ct - 1.0f), 0.5f * st);  // (T-1)/2
        float2 Tp  = make_float2(0.5f * (ct + 1.0f), 0.5f * st);  // (T+1)/2
        float2 iTp = make_float2(-Tp.y, Tp.x);                    // i*(T+1)/2
        float2 m00 = cmulh(cmulh(F, Tm), A);
        float2 m01 = cmulh(cmulh(F, iTp), Bb);
        float2 m10 = cmulh(iTp, A);
        float2 m11 = cmulh(make_float2(-Tm.x, -Tm.y), Bb);
        Msh[p * 4 + 0] = f2{m00.x, m00.y};
        Msh[p * 4 + 1] = f2{m01.x, m01.y};
        Msh[p * 4 + 2] = f2{m10.x, m10.y};
        Msh[p * 4 + 3] = f2{m11.x, m11.y};
    }
    __syncthreads();  // Msh visible to all waves

    // ---- pin all 48 matrix values to SGPRs (once per kernel) ----
    f2 M[48];
    #pragma unroll
    for (int k = 0; k < 24; ++k) {
        f4 two = *reinterpret_cast<const f4*>(&Msh[k * 2]);  // ds_read_b128
        M[k * 2 + 0] = rfl2(f2{two.x, two.y});
        M[k * 2 + 1] = rfl2(f2{two.z, two.w});
    }

    #pragma unroll
    for (int r = 0; r < 2; ++r) {
        f2 v[8];
        if (r == 0) {
            v[0] = f2{ra0.x, ia0.x}; v[1] = f2{ra0.y, ia0.y};
            v[2] = f2{ra0.z, ia0.z}; v[3] = f2{ra0.w, ia0.w};
            v[4] = f2{rb0.x, ib0.x}; v[5] = f2{rb0.y, ib0.y};
            v[6] = f2{rb0.z, ib0.z}; v[7] = f2{rb0.w, ib0.w};
        } else {
            v[0] = f2{ra1.x, ia1.x}; v[1] = f2{ra1.y, ia1.y};
            v[2] = f2{ra1.z, ia1.z}; v[3] = f2{ra1.w, ia1.w};
            v[4] = f2{rb1.x, ib1.x}; v[5] = f2{rb1.y, ib1.y};
            v[6] = f2{rb1.z, ib1.z}; v[7] = f2{rb1.w, ib1.w};
        }

        // ---- phase 1: bits 0,1,2 ----
        stagepk8<1>(v, M[0],  M[1],  M[2],  M[3]);
        stagepk8<2>(v, M[4],  M[5],  M[6],  M[7]);
        stagepk8<4>(v, M[8],  M[9],  M[10], M[11]);

        // ---- transpose A -> B (wave-region-local, no barrier) ----
        {
            f2* wp = lds + 9 * T;
            #pragma unroll
            for (int s = 0; s < 8; ++s) wp[s] = v[s];
        }
        {
            const f2* rp = lds + 72 * (T >> 3) + (T & 7);
            #pragma unroll
            for (int s = 0; s < 8; ++s) v[s] = rp[9 * s];
        }

        // ---- phase 2: bits 3,4,5 ----
        stagepk8<1>(v, M[12], M[13], M[14], M[15]);
        stagepk8<2>(v, M[16], M[17], M[18], M[19]);
        stagepk8<4>(v, M[20], M[21], M[22], M[23]);

        // ---- transpose B -> C (wave-region-local, no barrier) ----
        {
            f2* wp = lds + 72 * (T >> 3) + (T & 7);
            #pragma unroll
            for (int s = 0; s < 8; ++s) wp[9 * s] = v[s];
        }
        {
            const f2* rp = lds + 576 * (T >> 6) + (T & 63) + ((T & 63) >> 3);
            #pragma unroll
            for (int s = 0; s < 8; ++s) v[s] = rp[72 * s];
        }

        // ---- phase 3: bits 6,7,8 ----
        stagepk8<1>(v, M[24], M[25], M[26], M[27]);
        stagepk8<2>(v, M[28], M[29], M[30], M[31]);
        stagepk8<4>(v, M[32], M[33], M[34], M[35]);

        // ---- transpose C -> D: write C (own region), BARRIER, read D ----
        {
            f2* wp = lds + 576 * (T >> 6) + (T & 63) + ((T & 63) >> 3);
            #pragma unroll
            for (int s = 0; s < 8; ++s) wp[72 * s] = v[s];
        }
        __syncthreads();
        {
            const f2* rp = lds + T + (T >> 3);   // idx(s<<9 | T) = 576s + T + (T>>3)
            #pragma unroll
            for (int s = 0; s < 8; ++s) v[s] = rp[576 * s];
        }
        if (r == 0) __syncthreads();  // D-reads done before row 1's A-writes

        // ---- phase 4: bits 9,10,11 ----
        stagepk8<1>(v, M[36], M[37], M[38], M[39]);
        stagepk8<2>(v, M[40], M[41], M[42], M[43]);
        stagepk8<4>(v, M[44], M[45], M[46], M[47]);

        // ---- store (mapping D): i = s<<9 | T, wave-contiguous, non-temporal ----
        {
            float* po = out + (row0 + r) * (2 * NN);
            #pragma unroll
            for (int s = 0; s < 8; ++s) {
                int i = (s << 9) | T;
                __builtin_nontemporal_store(v[s].x, po + i);
                __builtin_nontemporal_store(v[s].y, po + NN + i);
            }
        }
    }
}

extern "C" void kernel_launch(void* const* d_in, const int* in_sizes, int n_in,
                              void* d_out, int out_size, void* d_ws, size_t ws_size,
                              hipStream_t stream) {
    const float* x      = (const float*)d_in[0];
    const float* alphas = (const float*)d_in[1];
    const float* betas  = (const float*)d_in[2];
    const float* thetas = (const float*)d_in[3];
    const float* phis   = (const float*)d_in[4];
    float* out = (float*)d_out;

    const int B = in_sizes[0] / (2 * NN);  // 2048

    hipLaunchKernelGGL(sq_layer, dim3(B / 2), dim3(512), 0, stream,
                       x, out, alphas, betas, thetas, phis);
}